// Round 1
// baseline (852.659 us; speedup 1.0000x reference)
//
#include <hip/hip_runtime.h>
#include <hip/hip_bf16.h>
#include <cstdint>

#define B_  4
#define S_  4096
#define DIN 1024
#define DH  128

// ---------------- Kernel 1: fused QKV projection ----------------
// grid = (B*S)/PBM blocks of 256 threads; each block: PBM rows x 128 cols x 3 mats
#define PBM 32
#define PBK 32

__global__ __launch_bounds__(256) void qkv_proj(
    const float* __restrict__ x,  const float* __restrict__ Wq,
    const float* __restrict__ Wk, const float* __restrict__ Wv,
    float* __restrict__ Q, float* __restrict__ K, float* __restrict__ V)
{
    __shared__ float xs[PBM][36];           // pad 36: float4-aligned, conflict-free
    __shared__ float wsm[3][PBK][DH];

    float acc[3][4][4];
    #pragma unroll
    for (int m = 0; m < 3; ++m)
        #pragma unroll
        for (int i = 0; i < 4; ++i)
            #pragma unroll
            for (int j = 0; j < 4; ++j) acc[m][i][j] = 0.f;

    const int t    = threadIdx.x;
    const int row0 = blockIdx.x * PBM;
    const int tx   = t & 31;   // cols 4*tx .. 4*tx+3
    const int ty   = t >> 5;   // rows 4*ty .. 4*ty+3
    const float* Wptr[3] = {Wq, Wk, Wv};

    for (int k0 = 0; k0 < DIN; k0 += PBK) {
        // x tile: 32x32 floats = 256 float4 = 1 per thread
        {
            int r = t >> 3, c4 = t & 7;
            *(float4*)&xs[r][c4 * 4] =
                *(const float4*)(x + (size_t)(row0 + r) * DIN + k0 + c4 * 4);
        }
        // W tiles: 3 * (32x128) floats = 3*1024 float4 = 12 per thread
        #pragma unroll
        for (int m = 0; m < 3; ++m) {
            const float* W = Wptr[m];
            #pragma unroll
            for (int i = 0; i < 4; ++i) {
                int idx = i * 256 + t;
                int r = idx >> 5, c4 = idx & 31;
                *(float4*)&wsm[m][r][c4 * 4] =
                    *(const float4*)(W + (size_t)(k0 + r) * DH + c4 * 4);
            }
        }
        __syncthreads();

        #pragma unroll
        for (int kk = 0; kk < PBK; kk += 4) {
            float xv[4][4];
            #pragma unroll
            for (int i = 0; i < 4; ++i)
                *(float4*)&xv[i][0] = *(const float4*)&xs[4 * ty + i][kk];
            #pragma unroll
            for (int e = 0; e < 4; ++e) {
                #pragma unroll
                for (int m = 0; m < 3; ++m) {
                    float w4[4];
                    *(float4*)&w4[0] = *(const float4*)&wsm[m][kk + e][4 * tx];
                    #pragma unroll
                    for (int i = 0; i < 4; ++i)
                        #pragma unroll
                        for (int j = 0; j < 4; ++j)
                            acc[m][i][j] = fmaf(xv[i][e], w4[j], acc[m][i][j]);
                }
            }
        }
        __syncthreads();
    }

    float* Optr[3] = {Q, K, V};
    #pragma unroll
    for (int m = 0; m < 3; ++m) {
        #pragma unroll
        for (int i = 0; i < 4; ++i) {
            float4 o;
            o.x = acc[m][i][0]; o.y = acc[m][i][1];
            o.z = acc[m][i][2]; o.w = acc[m][i][3];
            *(float4*)(Optr[m] + (size_t)(row0 + 4 * ty + i) * DH + 4 * tx) = o;
        }
    }
}

// ---------------- Kernel 2: flash attention, fp32 ----------------
#define QT 64
#define KT 64

__global__ __launch_bounds__(256) void flash_fp32(
    const float* __restrict__ Q, const float* __restrict__ K,
    const float* __restrict__ V, float* __restrict__ O)
{
    __shared__ float qs[QT][132];   // pad 132: float4-aligned, broadcast reads
    __shared__ float ks[KT][132];
    __shared__ float vs[KT][DH];
    __shared__ float ss[QT][KT + 1];
    __shared__ float m_s[QT], l_s[QT], f_s[QT];

    const int t  = threadIdx.x;
    const int b  = blockIdx.y, qt = blockIdx.x;
    const int qrow0 = b * S_ + qt * QT;
    const float scale = 0.08838834764831845f;  // 1/sqrt(128)

    // Q tile: 64x128 = 2048 float4 = 8 per thread
    #pragma unroll
    for (int i = 0; i < 8; ++i) {
        int idx = i * 256 + t;
        int r = idx >> 5, c4 = idx & 31;
        *(float4*)&qs[r][c4 * 4] =
            *(const float4*)(Q + (size_t)(qrow0 + r) * DH + c4 * 4);
    }
    if (t < QT) { m_s[t] = -3.0e38f; l_s[t] = 0.f; }

    float acc[4][8];
    #pragma unroll
    for (int i = 0; i < 4; ++i)
        #pragma unroll
        for (int h = 0; h < 8; ++h) acc[i][h] = 0.f;

    const int sx = t & 15, sy = t >> 4;   // scores: rows 4sy+i, cols sx+16j
    const int srow = t >> 2, sq = t & 3;  // softmax: 4 threads/row

    for (int kt = 0; kt < S_ / KT; ++kt) {
        __syncthreads();   // protect ks/vs/ss from prev iteration's readers
        const int krow0 = b * S_ + kt * KT;
        #pragma unroll
        for (int i = 0; i < 8; ++i) {
            int idx = i * 256 + t;
            int r = idx >> 5, c4 = idx & 31;
            *(float4*)&ks[r][c4 * 4] =
                *(const float4*)(K + (size_t)(krow0 + r) * DH + c4 * 4);
            *(float4*)&vs[r][c4 * 4] =
                *(const float4*)(V + (size_t)(krow0 + r) * DH + c4 * 4);
        }
        __syncthreads();

        // ---- scores: S = (Q . K^T) * scale ----
        float sacc[4][4];
        #pragma unroll
        for (int i = 0; i < 4; ++i)
            #pragma unroll
            for (int j = 0; j < 4; ++j) sacc[i][j] = 0.f;

        #pragma unroll 2
        for (int kk = 0; kk < DH; kk += 4) {
            float qv[4][4], kv[4][4];
            #pragma unroll
            for (int i = 0; i < 4; ++i)
                *(float4*)&qv[i][0] = *(const float4*)&qs[4 * sy + i][kk];
            #pragma unroll
            for (int j = 0; j < 4; ++j)
                *(float4*)&kv[j][0] = *(const float4*)&ks[sx + 16 * j][kk];
            #pragma unroll
            for (int e = 0; e < 4; ++e)
                #pragma unroll
                for (int i = 0; i < 4; ++i)
                    #pragma unroll
                    for (int j = 0; j < 4; ++j)
                        sacc[i][j] = fmaf(qv[i][e], kv[j][e], sacc[i][j]);
        }
        #pragma unroll
        for (int i = 0; i < 4; ++i)
            #pragma unroll
            for (int j = 0; j < 4; ++j)
                ss[4 * sy + i][sx + 16 * j] = sacc[i][j] * scale;
        __syncthreads();

        // ---- online softmax (4 threads per row, same wave) ----
        {
            float p[16];
            float mloc = -3.0e38f;
            #pragma unroll
            for (int c = 0; c < 16; ++c) {
                p[c] = ss[srow][16 * sq + c];
                mloc = fmaxf(mloc, p[c]);
            }
            mloc = fmaxf(mloc, __shfl_xor(mloc, 1));
            mloc = fmaxf(mloc, __shfl_xor(mloc, 2));
            float mold = m_s[srow];
            float mnew = fmaxf(mold, mloc);
            float ssum = 0.f;
            #pragma unroll
            for (int c = 0; c < 16; ++c) {
                float pe = __expf(p[c] - mnew);
                ss[srow][16 * sq + c] = pe;
                ssum += pe;
            }
            ssum += __shfl_xor(ssum, 1);
            ssum += __shfl_xor(ssum, 2);
            if (sq == 0) {
                float f = __expf(mold - mnew);
                l_s[srow] = l_s[srow] * f + ssum;
                m_s[srow] = mnew;
                f_s[srow] = f;
            }
        }
        __syncthreads();

        // ---- PV accumulate: rows 4sy+i, cols {4sx+c, 64+4sx+c} ----
        {
            #pragma unroll
            for (int i = 0; i < 4; ++i) {
                float f = f_s[4 * sy + i];
                #pragma unroll
                for (int h = 0; h < 8; ++h) acc[i][h] *= f;
            }
            #pragma unroll 4
            for (int j = 0; j < KT; ++j) {
                float pv[4];
                #pragma unroll
                for (int i = 0; i < 4; ++i) pv[i] = ss[4 * sy + i][j];
                float va[4], vb[4];
                *(float4*)&va[0] = *(const float4*)&vs[j][4 * sx];
                *(float4*)&vb[0] = *(const float4*)&vs[j][64 + 4 * sx];
                #pragma unroll
                for (int i = 0; i < 4; ++i) {
                    #pragma unroll
                    for (int c = 0; c < 4; ++c) {
                        acc[i][c]     = fmaf(pv[i], va[c], acc[i][c]);
                        acc[i][4 + c] = fmaf(pv[i], vb[c], acc[i][4 + c]);
                    }
                }
            }
        }
    }

    // ---- epilogue: divide by l, store ----
    #pragma unroll
    for (int i = 0; i < 4; ++i) {
        float inv = 1.0f / l_s[4 * sy + i];
        float4 oa, ob;
        oa.x = acc[i][0] * inv; oa.y = acc[i][1] * inv;
        oa.z = acc[i][2] * inv; oa.w = acc[i][3] * inv;
        ob.x = acc[i][4] * inv; ob.y = acc[i][5] * inv;
        ob.z = acc[i][6] * inv; ob.w = acc[i][7] * inv;
        *(float4*)(O + (size_t)(qrow0 + 4 * sy + i) * DH + 4 * sx)      = oa;
        *(float4*)(O + (size_t)(qrow0 + 4 * sy + i) * DH + 64 + 4 * sx) = ob;
    }
}

extern "C" void kernel_launch(void* const* d_in, const int* in_sizes, int n_in,
                              void* d_out, int out_size, void* d_ws, size_t ws_size,
                              hipStream_t stream) {
    const float* x  = (const float*)d_in[0];
    const float* Wq = (const float*)d_in[1];
    const float* Wk = (const float*)d_in[2];
    const float* Wv = (const float*)d_in[3];
    float* out = (float*)d_out;

    const size_t R = (size_t)B_ * S_;
    float* Qw = (float*)d_ws;
    float* Kw = Qw + R * DH;
    float* Vw = Kw + R * DH;

    qkv_proj<<<dim3((int)(R / PBM)), 256, 0, stream>>>(x, Wq, Wk, Wv, Qw, Kw, Vw);
    flash_fp32<<<dim3(S_ / QT, B_), 256, 0, stream>>>(Qw, Kw, Vw, out);
}

// Round 2
// 298.816 us; speedup vs baseline: 2.8535x; 2.8535x over previous
//
#include <hip/hip_runtime.h>
#include <cstdint>

#define B_  4
#define S_  4096
#define DIN 1024
#define DH  128
#define SCALE 0.08838834764831845f

typedef short bf16x8 __attribute__((ext_vector_type(8)));
typedef float f32x4 __attribute__((ext_vector_type(4)));
typedef int   int4v __attribute__((ext_vector_type(4)));
typedef unsigned short u16;
typedef unsigned int   u32;

#define MFMA16(a, b, c) __builtin_amdgcn_mfma_f32_16x16x32_bf16(a, b, c, 0, 0, 0)

#define GLOAD_LDS16(g, l) __builtin_amdgcn_global_load_lds( \
    (const __attribute__((address_space(1))) void*)(g),     \
    (__attribute__((address_space(3))) void*)(l), 16, 0, 0)

__device__ inline u16 bf16_rn(float f) {
    union { float f; u32 u; } v; v.f = f;
    u32 r = v.u + 0x7FFFu + ((v.u >> 16) & 1u);
    return (u16)(r >> 16);
}
__device__ inline float bf16_f(u16 h) {
    union { u32 u; float f; } v; v.u = ((u32)h) << 16; return v.f;
}
__device__ inline u32 pk2(float a, float b) {
    return (u32)bf16_rn(a) | ((u32)bf16_rn(b) << 16);
}

// ---------------- Kernel 1: fused QKV projection (fp32 compute) ----------------
// Outputs: Qhi/Qlo row-major [16384][128] bf16 (scale folded in);
// Khi/Klo tiled [b][kt][64][128] bf16 with 16B-granule XOR(kr&15) swizzle;
// Vt tiled-transposed [b][kt][128][64] bf16 with granule XOR(d&7) swizzle.
#define PBM 32
#define PBK 32

__global__ __launch_bounds__(256) void qkv_proj(
    const float* __restrict__ x,  const float* __restrict__ Wq,
    const float* __restrict__ Wk, const float* __restrict__ Wv,
    u16* __restrict__ qhi, u16* __restrict__ qlo,
    u16* __restrict__ khi, u16* __restrict__ klo,
    u16* __restrict__ vt)
{
    __shared__ float xs[PBM][36];
    __shared__ float wsm[3][PBK][DH];

    float acc[3][4][4];
    #pragma unroll
    for (int m = 0; m < 3; ++m)
        #pragma unroll
        for (int i = 0; i < 4; ++i)
            #pragma unroll
            for (int j = 0; j < 4; ++j) acc[m][i][j] = 0.f;

    const int t    = threadIdx.x;
    const int row0 = blockIdx.x * PBM;
    const int tx   = t & 31;
    const int ty   = t >> 5;
    const float* Wptr[3] = {Wq, Wk, Wv};

    for (int k0 = 0; k0 < DIN; k0 += PBK) {
        {
            int r = t >> 3, c4 = t & 7;
            *(float4*)&xs[r][c4 * 4] =
                *(const float4*)(x + (size_t)(row0 + r) * DIN + k0 + c4 * 4);
        }
        #pragma unroll
        for (int m = 0; m < 3; ++m) {
            const float* W = Wptr[m];
            #pragma unroll
            for (int i = 0; i < 4; ++i) {
                int idx = i * 256 + t;
                int r = idx >> 5, c4 = idx & 31;
                *(float4*)&wsm[m][r][c4 * 4] =
                    *(const float4*)(W + (size_t)(k0 + r) * DH + c4 * 4);
            }
        }
        __syncthreads();

        #pragma unroll
        for (int kk = 0; kk < PBK; kk += 4) {
            float xv[4][4];
            #pragma unroll
            for (int i = 0; i < 4; ++i)
                *(float4*)&xv[i][0] = *(const float4*)&xs[4 * ty + i][kk];
            #pragma unroll
            for (int e = 0; e < 4; ++e) {
                #pragma unroll
                for (int m = 0; m < 3; ++m) {
                    float w4[4];
                    *(float4*)&w4[0] = *(const float4*)&wsm[m][kk + e][4 * tx];
                    #pragma unroll
                    for (int i = 0; i < 4; ++i)
                        #pragma unroll
                        for (int j = 0; j < 4; ++j)
                            acc[m][i][j] = fmaf(xv[i][e], w4[j], acc[m][i][j]);
                }
            }
        }
        __syncthreads();
    }

    #pragma unroll
    for (int i = 0; i < 4; ++i) {
        int r  = row0 + 4 * ty + i;          // global row 0..16383
        int b  = r >> 12, s = r & 4095;
        int kt = s >> 6,  kr = s & 63;

        // ---- Q: scale fold + hi/lo split, row-major ----
        {
            u16 h[4], lo[4];
            #pragma unroll
            for (int j = 0; j < 4; ++j) {
                float q = acc[0][i][j] * SCALE;
                h[j]  = bf16_rn(q);
                lo[j] = bf16_rn(q - bf16_f(h[j]));
            }
            uint2 ph, pl;
            ph.x = (u32)h[0] | ((u32)h[1] << 16);  ph.y = (u32)h[2] | ((u32)h[3] << 16);
            pl.x = (u32)lo[0] | ((u32)lo[1] << 16); pl.y = (u32)lo[2] | ((u32)lo[3] << 16);
            *(uint2*)(qhi + (size_t)r * DH + 4 * tx) = ph;
            *(uint2*)(qlo + (size_t)r * DH + 4 * tx) = pl;
        }
        // ---- K: tiled + granule swizzle ----
        {
            u16 h[4], lo[4];
            #pragma unroll
            for (int j = 0; j < 4; ++j) {
                float kv = acc[1][i][j];
                h[j]  = bf16_rn(kv);
                lo[j] = bf16_rn(kv - bf16_f(h[j]));
            }
            int pg = (tx >> 1) ^ (kr & 15);
            size_t ka = (((size_t)(b * 64 + kt)) * 64 + kr) * 128 + pg * 8 + (tx & 1) * 4;
            uint2 ph, pl;
            ph.x = (u32)h[0] | ((u32)h[1] << 16);  ph.y = (u32)h[2] | ((u32)h[3] << 16);
            pl.x = (u32)lo[0] | ((u32)lo[1] << 16); pl.y = (u32)lo[2] | ((u32)lo[3] << 16);
            *(uint2*)(khi + ka) = ph;
            *(uint2*)(klo + ka) = pl;
        }
        // ---- V: transposed tile + granule swizzle (scalar u16 stores) ----
        {
            #pragma unroll
            for (int j = 0; j < 4; ++j) {
                int d = 4 * tx + j;
                size_t va = (((size_t)(b * 64 + kt)) * 128 + d) * 64
                          + (((kr >> 3) ^ (d & 7)) * 8) + (kr & 7);
                vt[va] = bf16_rn(acc[2][i][j]);
            }
        }
    }
}

// ---------------- Kernel 2: flash attention, split-bf16 MFMA ----------------
// grid (64, 4): 256 blocks; 4 waves; wave owns 16 q-rows; KT=64; NT=64 tiles.
#define TILE_BYTES 16384          // one 64x128 bf16 tile
#define BUF_BYTES  49152          // khi + klo + vt

__global__ __launch_bounds__(256) void flash_mfma(
    const u16* __restrict__ qhi, const u16* __restrict__ qlo,
    const u16* __restrict__ khi, const u16* __restrict__ klo,
    const u16* __restrict__ vt,  float* __restrict__ O)
{
    __shared__ __align__(16) char smem[2 * BUF_BYTES];

    const int tid  = threadIdx.x;
    const int wave = tid >> 6;
    const int lane = tid & 63;
    const int l15  = lane & 15;
    const int g    = lane >> 4;           // 0..3
    const int qt   = blockIdx.x;
    const int b    = blockIdx.y;

    // ---- Q fragments (B-operand), in registers, hi+lo ----
    const size_t qglob = (size_t)b * S_ + qt * 64 + wave * 16 + l15;
    bf16x8 qh[4], ql[4];
    #pragma unroll
    for (int ks = 0; ks < 4; ++ks) {
        qh[ks] = *(const bf16x8*)(qhi + qglob * DH + 32 * ks + 8 * g);
        ql[ks] = *(const bf16x8*)(qlo + qglob * DH + 32 * ks + 8 * g);
    }

    f32x4 Oacc[8];
    #pragma unroll
    for (int dt = 0; dt < 8; ++dt)
        #pragma unroll
        for (int r = 0; r < 4; ++r) Oacc[dt][r] = 0.f;

    float m_run = -3.0e38f, l_run = 0.f;

    // per-lane precomputed LDS offsets
    int koff[4];   // khi/klo: per ks, add nt*4096
    #pragma unroll
    for (int ks = 0; ks < 4; ++ks)
        koff[ks] = (((4 * ks + g) ^ l15) << 4) + (l15 << 8);
    int voff[2];   // vt: per kw, add (16*dt+l15)*128
    #pragma unroll
    for (int kw = 0; kw < 2; ++kw)
        voff[kw] = (((4 * kw + g) ^ (l15 & 7)) << 4);

    const char* kbase = (const char*)(khi + ((size_t)b * 64) * 8192);
    const char* lbase = (const char*)(klo + ((size_t)b * 64) * 8192);
    const char* vbase = (const char*)(vt  + ((size_t)b * 64) * 8192);

    // ---- staging: 48 KB per K-tile via global_load_lds ----
    auto stage = [&](int bufi, int kt) {
        const char* sk = kbase + (size_t)kt * TILE_BYTES;
        const char* sl = lbase + (size_t)kt * TILE_BYTES;
        const char* sv = vbase + (size_t)kt * TILE_BYTES;
        char* dk = smem + bufi * BUF_BYTES;
        #pragma unroll
        for (int c = 0; c < 4; ++c) {
            int o = tid * 16 + c * 4096;
            GLOAD_LDS16(sk + o, dk + o);
            GLOAD_LDS16(sl + o, dk + TILE_BYTES + o);
            GLOAD_LDS16(sv + o, dk + 2 * TILE_BYTES + o);
        }
    };

    stage(0, 0);
    __syncthreads();

    int buf = 0;
    for (int kt = 0; kt < 64; ++kt) {
        if (kt < 63) stage(buf ^ 1, kt + 1);

        const char* bk = smem + buf * BUF_BYTES;
        const char* bl = bk + TILE_BYTES;
        const char* bv = bk + 2 * TILE_BYTES;

        // ---- QK^T (swapped: A=K, B=Q), split-bf16 3-MFMA ----
        f32x4 sacc[4];
        #pragma unroll
        for (int nt = 0; nt < 4; ++nt)
            #pragma unroll
            for (int r = 0; r < 4; ++r) sacc[nt][r] = 0.f;

        #pragma unroll
        for (int ks = 0; ks < 4; ++ks) {
            #pragma unroll
            for (int nt = 0; nt < 4; ++nt) {
                bf16x8 kh = *(const bf16x8*)(bk + nt * 4096 + koff[ks]);
                bf16x8 kl = *(const bf16x8*)(bl + nt * 4096 + koff[ks]);
                sacc[nt] = MFMA16(kh, qh[ks], sacc[nt]);
                sacc[nt] = MFMA16(kh, ql[ks], sacc[nt]);
                sacc[nt] = MFMA16(kl, qh[ks], sacc[nt]);
            }
        }
        // lane holds S[q = l15][k = 16*nt + 4*g + r] (scale already folded in Q)

        // ---- online softmax, fully in-register ----
        float mloc = -3.0e38f;
        #pragma unroll
        for (int nt = 0; nt < 4; ++nt)
            #pragma unroll
            for (int r = 0; r < 4; ++r) mloc = fmaxf(mloc, sacc[nt][r]);
        mloc = fmaxf(mloc, __shfl_xor(mloc, 16));
        mloc = fmaxf(mloc, __shfl_xor(mloc, 32));
        float mnew = fmaxf(m_run, mloc);
        float fsc  = __expf(m_run - mnew);
        m_run = mnew;

        float ps = 0.f;
        u32 pk[4][2];
        #pragma unroll
        for (int nt = 0; nt < 4; ++nt) {
            float p0 = __expf(sacc[nt][0] - mnew);
            float p1 = __expf(sacc[nt][1] - mnew);
            float p2 = __expf(sacc[nt][2] - mnew);
            float p3 = __expf(sacc[nt][3] - mnew);
            ps += (p0 + p1) + (p2 + p3);
            pk[nt][0] = pk2(p0, p1);
            pk[nt][1] = pk2(p2, p3);
        }
        ps += __shfl_xor(ps, 16);
        ps += __shfl_xor(ps, 32);
        l_run = l_run * fsc + ps;

        // ---- rescale O accumulator (O rows are q_local = 4*g + r) ----
        float frs[4];
        #pragma unroll
        for (int r = 0; r < 4; ++r) frs[r] = __shfl(fsc, 4 * g + r);
        #pragma unroll
        for (int dt = 0; dt < 8; ++dt)
            #pragma unroll
            for (int r = 0; r < 4; ++r) Oacc[dt][r] *= frs[r];

        // ---- PV: A = P (assembled via shfl), B = V from swizzled Vt ----
        const int s0 = l15 | ((2 * (g & 1)) << 4);
        const int s1 = s0 + 16;
        const int hiHalf = g >> 1;
        #pragma unroll
        for (int kw = 0; kw < 2; ++kw) {
            u32 x0 = __shfl(pk[2 * kw][0], s0),     y0 = __shfl(pk[2 * kw + 1][0], s0);
            u32 x1 = __shfl(pk[2 * kw][1], s0),     y1 = __shfl(pk[2 * kw + 1][1], s0);
            u32 x2 = __shfl(pk[2 * kw][0], s1),     y2 = __shfl(pk[2 * kw + 1][0], s1);
            u32 x3 = __shfl(pk[2 * kw][1], s1),     y3 = __shfl(pk[2 * kw + 1][1], s1);
            int4v ai;
            ai[0] = (int)(hiHalf ? y0 : x0);
            ai[1] = (int)(hiHalf ? y1 : x1);
            ai[2] = (int)(hiHalf ? y2 : x2);
            ai[3] = (int)(hiHalf ? y3 : x3);
            bf16x8 pa = __builtin_bit_cast(bf16x8, ai);
            #pragma unroll
            for (int dt = 0; dt < 8; ++dt) {
                bf16x8 vf = *(const bf16x8*)(bv + (16 * dt + l15) * 128 + voff[kw]);
                Oacc[dt] = MFMA16(pa, vf, Oacc[dt]);
            }
        }

        __syncthreads();
        buf ^= 1;
    }

    // ---- epilogue: normalize + store fp32 ----
    float linv[4];
    #pragma unroll
    for (int r = 0; r < 4; ++r) linv[r] = 1.0f / __shfl(l_run, 4 * g + r);

    const size_t orow0 = (size_t)b * S_ + qt * 64 + wave * 16;
    #pragma unroll
    for (int dt = 0; dt < 8; ++dt)
        #pragma unroll
        for (int r = 0; r < 4; ++r)
            O[(orow0 + 4 * g + r) * DH + 16 * dt + l15] = Oacc[dt][r] * linv[r];
}

extern "C" void kernel_launch(void* const* d_in, const int* in_sizes, int n_in,
                              void* d_out, int out_size, void* d_ws, size_t ws_size,
                              hipStream_t stream) {
    const float* x  = (const float*)d_in[0];
    const float* Wq = (const float*)d_in[1];
    const float* Wk = (const float*)d_in[2];
    const float* Wv = (const float*)d_in[3];
    float* out = (float*)d_out;

    const size_t R = (size_t)B_ * S_;          // 16384
    const size_t SZ = R * DH;                  // 2,097,152 elems per region
    u16* qhi = (u16*)d_ws;
    u16* qlo = qhi + SZ;
    u16* khi = qlo + SZ;
    u16* klo = khi + SZ;
    u16* vt  = klo + SZ;

    qkv_proj<<<dim3((int)(R / PBM)), 256, 0, stream>>>(x, Wq, Wk, Wv,
                                                       qhi, qlo, khi, klo, vt);
    flash_mfma<<<dim3(S_ / 64, B_), 256, 0, stream>>>(qhi, qlo, khi, klo, vt, out);
}

// Round 3
// 161.094 us; speedup vs baseline: 5.2929x; 1.8549x over previous
//
#include <hip/hip_runtime.h>
#include <cstdint>

#define B_  4
#define S_  4096
#define DIN 1024
#define DH  128
#define SCALE 0.08838834764831845f

typedef short bf16x8 __attribute__((ext_vector_type(8)));
typedef float f32x4 __attribute__((ext_vector_type(4)));
typedef unsigned short u16;
typedef unsigned int   u32;

#define MFMA16(a, b, c) __builtin_amdgcn_mfma_f32_16x16x32_bf16(a, b, c, 0, 0, 0)

#define GLOAD_LDS16(g, l) __builtin_amdgcn_global_load_lds( \
    (const __attribute__((address_space(1))) void*)(g),     \
    (__attribute__((address_space(3))) void*)(l), 16, 0, 0)

__device__ inline u16 bf16_rn(float f) {
    union { float f; u32 u; } v; v.f = f;
    u32 r = v.u + 0x7FFFu + ((v.u >> 16) & 1u);
    return (u16)(r >> 16);
}
__device__ inline u32 pk2(float a, float b) {
    return (u32)bf16_rn(a) | ((u32)bf16_rn(b) << 16);
}
// split fp32 pair -> packed hi (trunc) + packed lo (RN of residual)
__device__ inline void split2(float a, float b, u32& hi, u32& lo) {
    u32 ua = __builtin_bit_cast(u32, a), ub = __builtin_bit_cast(u32, b);
    u32 ha = ua & 0xFFFF0000u, hb = ub & 0xFFFF0000u;
    hi = (ua >> 16) | hb;
    float la = a - __builtin_bit_cast(float, ha);
    float lb = b - __builtin_bit_cast(float, hb);
    lo = (u32)bf16_rn(la) | ((u32)bf16_rn(lb) << 16);
}

// ---------------- Kernel 0: W convert/split/transpose/swizzle ----------------
// Out: wThi/wTlo [mat][kstep(16)][n(128)][k(64), granule-swizzled]; scale folded into Wq.
__global__ __launch_bounds__(256) void wconv(
    const float* __restrict__ Wq, const float* __restrict__ Wk, const float* __restrict__ Wv,
    u16* __restrict__ whi, u16* __restrict__ wlo)
{
    int bid = blockIdx.x;                       // 0..1535
    int mat = bid >> 9;
    int i = ((bid & 511) << 8) | threadIdx.x;   // 0..131071 within mat
    int k = i >> 7, n = i & 127;
    const float* W = (mat == 0) ? Wq : (mat == 1 ? Wk : Wv);
    float v = W[i];
    if (mat == 0) v *= SCALE;
    u32 u = __builtin_bit_cast(u32, v);
    float lo = v - __builtin_bit_cast(float, u & 0xFFFF0000u);
    int kt = k >> 6, kq = (k >> 3) & 7, j = k & 7;
    size_t pos = (((size_t)(mat * 16 + kt) * 128 + n) << 6)
               + (size_t)(((kq ^ (n & 7)) << 3) + j);
    whi[pos] = (u16)(u >> 16);
    wlo[pos] = bf16_rn(lo);
}

// ---------------- Kernel 1: QKV projection via split-bf16 MFMA ----------------
// grid (256, 3); block = 64 rows x 128 cols of one matrix; 4 waves (32x64 each).
__global__ __launch_bounds__(256, 3) void qkv_mfma(
    const float* __restrict__ x,
    const u16* __restrict__ wThi, const u16* __restrict__ wTlo,
    u16* __restrict__ qhi, u16* __restrict__ qlo,
    u16* __restrict__ khi, u16* __restrict__ klo, u16* __restrict__ vt)
{
    __shared__ __align__(16) char lds[49152];
    char* xh_l = lds;              // [64 rows][128 B] granule-swizzled
    char* xl_l = lds + 8192;
    char* wh_l = lds + 16384;      // [128 n][128 B] granule-swizzled
    char* wl_l = lds + 32768;

    const int t    = threadIdx.x;
    const int mat  = blockIdx.y;
    const int row0 = blockIdx.x * 64;
    const int lane = t & 63, wave = t >> 6;
    const int l15  = lane & 15, g = lane >> 4;
    const int wr   = wave >> 1, wc = wave & 1;

    f32x4 acc[2][4];
    #pragma unroll
    for (int rt = 0; rt < 2; ++rt)
        #pragma unroll
        for (int nt = 0; nt < 4; ++nt)
            #pragma unroll
            for (int r = 0; r < 4; ++r) acc[rt][nt][r] = 0.f;

    const int xr = t >> 2, xc = t & 3;
    const float* xsrc = x + (size_t)(row0 + xr) * DIN + xc * 16;
    const int wg0 = ((2 * xc) ^ (xr & 7)) << 4;
    const int wg1 = ((2 * xc + 1) ^ (xr & 7)) << 4;

    for (int s = 0; s < 16; ++s) {
        // ---- x: load 16 fp32, split, write swizzled LDS ----
        float4 f0 = *(const float4*)(xsrc + s * 64 + 0);
        float4 f1 = *(const float4*)(xsrc + s * 64 + 4);
        float4 f2 = *(const float4*)(xsrc + s * 64 + 8);
        float4 f3 = *(const float4*)(xsrc + s * 64 + 12);
        uint4 hA, lA, hB, lB;
        split2(f0.x, f0.y, hA.x, lA.x); split2(f0.z, f0.w, hA.y, lA.y);
        split2(f1.x, f1.y, hA.z, lA.z); split2(f1.z, f1.w, hA.w, lA.w);
        split2(f2.x, f2.y, hB.x, lB.x); split2(f2.z, f2.w, hB.y, lB.y);
        split2(f3.x, f3.y, hB.z, lB.z); split2(f3.z, f3.w, hB.w, lB.w);
        *(uint4*)(xh_l + xr * 128 + wg0) = hA;
        *(uint4*)(xh_l + xr * 128 + wg1) = hB;
        if (mat != 2) {
            *(uint4*)(xl_l + xr * 128 + wg0) = lA;
            *(uint4*)(xl_l + xr * 128 + wg1) = lB;
        }
        // ---- W: stage pre-swizzled tiles (bf16) ----
        const char* wsh = (const char*)wThi + (size_t)(mat * 16 + s) * 16384;
        #pragma unroll
        for (int c = 0; c < 4; ++c) {
            int o = t * 16 + c * 4096;
            GLOAD_LDS16(wsh + o, wh_l + o);
        }
        if (mat != 2) {
            const char* wsl = (const char*)wTlo + (size_t)(mat * 16 + s) * 16384;
            #pragma unroll
            for (int c = 0; c < 4; ++c) {
                int o = t * 16 + c * 4096;
                GLOAD_LDS16(wsl + o, wl_l + o);
            }
        }
        __syncthreads();

        // ---- MFMA: acc += x . W ----
        #pragma unroll
        for (int ks = 0; ks < 2; ++ks) {
            bf16x8 xa[2], xb[2];
            #pragma unroll
            for (int rt = 0; rt < 2; ++rt) {
                int row = wr * 32 + rt * 16 + l15;
                int off = row * 128 + (((ks * 4 + g) ^ (row & 7)) << 4);
                xa[rt] = *(const bf16x8*)(xh_l + off);
                if (mat != 2) xb[rt] = *(const bf16x8*)(xl_l + off);
            }
            #pragma unroll
            for (int nt = 0; nt < 4; ++nt) {
                int n = wc * 64 + nt * 16 + l15;
                int woff = n * 128 + (((ks * 4 + g) ^ (n & 7)) << 4);
                bf16x8 wh = *(const bf16x8*)(wh_l + woff);
                #pragma unroll
                for (int rt = 0; rt < 2; ++rt)
                    acc[rt][nt] = MFMA16(xa[rt], wh, acc[rt][nt]);
                if (mat != 2) {
                    bf16x8 wl = *(const bf16x8*)(wl_l + woff);
                    #pragma unroll
                    for (int rt = 0; rt < 2; ++rt) {
                        acc[rt][nt] = MFMA16(xa[rt], wl, acc[rt][nt]);
                        acc[rt][nt] = MFMA16(xb[rt], wh, acc[rt][nt]);
                    }
                }
            }
        }
        __syncthreads();
    }

    // ---- epilogue: emit flash-ready layouts ----
    #pragma unroll
    for (int rt = 0; rt < 2; ++rt) {
        #pragma unroll
        for (int reg = 0; reg < 4; ++reg) {
            int r  = row0 + wr * 32 + rt * 16 + 4 * g + reg;
            int bb = r >> 12, sr = r & 4095, kt = sr >> 6, kr = sr & 63;
            #pragma unroll
            for (int nt = 0; nt < 4; ++nt) {
                float v = acc[rt][nt][reg];
                int c = wc * 64 + nt * 16 + l15;
                if (mat == 0) {
                    u32 u = __builtin_bit_cast(u32, v);
                    float lo = v - __builtin_bit_cast(float, u & 0xFFFF0000u);
                    size_t o = (size_t)r * DH + c;
                    qhi[o] = (u16)(u >> 16);
                    qlo[o] = bf16_rn(lo);
                } else if (mat == 1) {
                    u32 u = __builtin_bit_cast(u32, v);
                    float lo = v - __builtin_bit_cast(float, u & 0xFFFF0000u);
                    size_t o = ((size_t)(bb * 64 + kt) * 64 + kr) * 128
                             + (((c >> 3) ^ (kr & 15)) << 3) + (c & 7);
                    khi[o] = (u16)(u >> 16);
                    klo[o] = bf16_rn(lo);
                } else {
                    size_t o = ((size_t)(bb * 64 + kt) * 128 + c) * 64
                             + (((kr >> 3) ^ (c & 7)) << 3) + (kr & 7);
                    vt[o] = bf16_rn(v);
                }
            }
        }
    }
}

// ---------------- Kernel 2: flash attention, 32 q-rows/wave, kt-split ----------------
template <int NSPLIT>
__global__ __launch_bounds__(256, 1) void flash(
    const u16* __restrict__ qhi, const u16* __restrict__ qlo,
    const u16* __restrict__ khi, const u16* __restrict__ klo,
    const u16* __restrict__ vt,
    float* __restrict__ out, float2* __restrict__ ml)
{
    __shared__ __align__(16) char smem[2 * 49152];
    constexpr int NT = 64 / NSPLIT;

    const int tid  = threadIdx.x;
    const int wave = tid >> 6, lane = tid & 63;
    const int l15  = lane & 15, g = lane >> 4;
    const int bid  = blockIdx.x;
    int b, z, qt;
    if (NSPLIT == 2) { int xcd = bid & 7; b = xcd >> 1; z = xcd & 1; qt = bid >> 3; }
    else             { b = bid & 3; z = 0; qt = bid >> 2; }

    const int q0row = b * S_ + qt * 128 + wave * 32;

    bf16x8 qh[2][4], ql[2][4];
    #pragma unroll
    for (int h = 0; h < 2; ++h)
        #pragma unroll
        for (int ks = 0; ks < 4; ++ks) {
            size_t qa = (size_t)(q0row + 16 * h + l15) * DH + 32 * ks + 8 * g;
            qh[h][ks] = *(const bf16x8*)(qhi + qa);
            ql[h][ks] = *(const bf16x8*)(qlo + qa);
        }

    f32x4 O0[8], O1[8];
    #pragma unroll
    for (int dt = 0; dt < 8; ++dt)
        #pragma unroll
        for (int r = 0; r < 4; ++r) { O0[dt][r] = 0.f; O1[dt][r] = 0.f; }

    float m0 = -3.0e38f, l0 = 0.f, m1 = -3.0e38f, l1 = 0.f;

    int koff[4];
    #pragma unroll
    for (int ks = 0; ks < 4; ++ks)
        koff[ks] = (((4 * ks + g) ^ l15) << 4) + (l15 << 8);
    int voff[2];
    #pragma unroll
    for (int kw = 0; kw < 2; ++kw)
        voff[kw] = (((4 * kw + g) ^ (l15 & 7)) << 4);

    const char* kbase = (const char*)(khi + (size_t)b * 64 * 8192);
    const char* lbase = (const char*)(klo + (size_t)b * 64 * 8192);
    const char* vbase = (const char*)(vt  + (size_t)b * 64 * 8192);
    const int kt0 = z * NT;

    auto stage = [&](int bufi, int ktl) {
        const char* sk = kbase + (size_t)(kt0 + ktl) * 16384;
        const char* sl = lbase + (size_t)(kt0 + ktl) * 16384;
        const char* sv = vbase + (size_t)(kt0 + ktl) * 16384;
        char* dk = smem + bufi * 49152;
        #pragma unroll
        for (int c = 0; c < 4; ++c) {
            int o = tid * 16 + c * 4096;
            GLOAD_LDS16(sk + o, dk + o);
            GLOAD_LDS16(sl + o, dk + 16384 + o);
            GLOAD_LDS16(sv + o, dk + 32768 + o);
        }
    };

    stage(0, 0);
    __syncthreads();

    int buf = 0;
    for (int ktl = 0; ktl < NT; ++ktl) {
        if (ktl < NT - 1) stage(buf ^ 1, ktl + 1);

        const char* bk = smem + buf * 49152;
        const char* bl = bk + 16384;
        const char* bv = bk + 32768;

        f32x4 s0[4], s1[4];
        #pragma unroll
        for (int nt = 0; nt < 4; ++nt)
            #pragma unroll
            for (int r = 0; r < 4; ++r) { s0[nt][r] = 0.f; s1[nt][r] = 0.f; }

        #pragma unroll
        for (int ks = 0; ks < 4; ++ks) {
            #pragma unroll
            for (int nt = 0; nt < 4; ++nt) {
                bf16x8 kh = *(const bf16x8*)(bk + nt * 4096 + koff[ks]);
                bf16x8 kl = *(const bf16x8*)(bl + nt * 4096 + koff[ks]);
                s0[nt] = MFMA16(kh, qh[0][ks], s0[nt]);
                s0[nt] = MFMA16(kh, ql[0][ks], s0[nt]);
                s0[nt] = MFMA16(kl, qh[0][ks], s0[nt]);
                s1[nt] = MFMA16(kh, qh[1][ks], s1[nt]);
                s1[nt] = MFMA16(kh, ql[1][ks], s1[nt]);
                s1[nt] = MFMA16(kl, qh[1][ks], s1[nt]);
            }
        }

        // ---- softmax half 0 ----
        u32 pk0[4][2], pk1[4][2];
        float fsc0, fsc1;
        {
            float mloc = -3.0e38f;
            #pragma unroll
            for (int nt = 0; nt < 4; ++nt)
                #pragma unroll
                for (int r = 0; r < 4; ++r) mloc = fmaxf(mloc, s0[nt][r]);
            mloc = fmaxf(mloc, __shfl_xor(mloc, 16));
            mloc = fmaxf(mloc, __shfl_xor(mloc, 32));
            float mnew = fmaxf(m0, mloc);
            fsc0 = __expf(m0 - mnew);
            m0 = mnew;
            float ps = 0.f;
            #pragma unroll
            for (int nt = 0; nt < 4; ++nt) {
                float p0 = __expf(s0[nt][0] - mnew);
                float p1 = __expf(s0[nt][1] - mnew);
                float p2 = __expf(s0[nt][2] - mnew);
                float p3 = __expf(s0[nt][3] - mnew);
                ps += (p0 + p1) + (p2 + p3);
                pk0[nt][0] = pk2(p0, p1);
                pk0[nt][1] = pk2(p2, p3);
            }
            ps += __shfl_xor(ps, 16);
            ps += __shfl_xor(ps, 32);
            l0 = l0 * fsc0 + ps;
        }
        // ---- softmax half 1 ----
        {
            float mloc = -3.0e38f;
            #pragma unroll
            for (int nt = 0; nt < 4; ++nt)
                #pragma unroll
                for (int r = 0; r < 4; ++r) mloc = fmaxf(mloc, s1[nt][r]);
            mloc = fmaxf(mloc, __shfl_xor(mloc, 16));
            mloc = fmaxf(mloc, __shfl_xor(mloc, 32));
            float mnew = fmaxf(m1, mloc);
            fsc1 = __expf(m1 - mnew);
            m1 = mnew;
            float ps = 0.f;
            #pragma unroll
            for (int nt = 0; nt < 4; ++nt) {
                float p0 = __expf(s1[nt][0] - mnew);
                float p1 = __expf(s1[nt][1] - mnew);
                float p2 = __expf(s1[nt][2] - mnew);
                float p3 = __expf(s1[nt][3] - mnew);
                ps += (p0 + p1) + (p2 + p3);
                pk1[nt][0] = pk2(p0, p1);
                pk1[nt][1] = pk2(p2, p3);
            }
            ps += __shfl_xor(ps, 16);
            ps += __shfl_xor(ps, 32);
            l1 = l1 * fsc1 + ps;
        }

        // ---- rescale O ----
        float fr0[4], fr1[4];
        #pragma unroll
        for (int r = 0; r < 4; ++r) {
            fr0[r] = __shfl(fsc0, 4 * g + r);
            fr1[r] = __shfl(fsc1, 4 * g + r);
        }
        #pragma unroll
        for (int dt = 0; dt < 8; ++dt)
            #pragma unroll
            for (int r = 0; r < 4; ++r) {
                O0[dt][r] *= fr0[r];
                O1[dt][r] *= fr1[r];
            }

        // ---- PV ----
        const int s0l = l15 | ((2 * (g & 1)) << 4);
        const int s1l = s0l + 16;
        const int hiH = g >> 1;
        #pragma unroll
        for (int kw = 0; kw < 2; ++kw) {
            u32 a0, a1, a2, a3, c0, c1, c2, c3;
            {
                u32 x0 = __shfl(pk0[2 * kw][0], s0l), y0 = __shfl(pk0[2 * kw + 1][0], s0l);
                u32 x1 = __shfl(pk0[2 * kw][1], s0l), y1 = __shfl(pk0[2 * kw + 1][1], s0l);
                u32 x2 = __shfl(pk0[2 * kw][0], s1l), y2 = __shfl(pk0[2 * kw + 1][0], s1l);
                u32 x3 = __shfl(pk0[2 * kw][1], s1l), y3 = __shfl(pk0[2 * kw + 1][1], s1l);
                a0 = hiH ? y0 : x0; a1 = hiH ? y1 : x1;
                a2 = hiH ? y2 : x2; a3 = hiH ? y3 : x3;
            }
            {
                u32 x0 = __shfl(pk1[2 * kw][0], s0l), y0 = __shfl(pk1[2 * kw + 1][0], s0l);
                u32 x1 = __shfl(pk1[2 * kw][1], s0l), y1 = __shfl(pk1[2 * kw + 1][1], s0l);
                u32 x2 = __shfl(pk1[2 * kw][0], s1l), y2 = __shfl(pk1[2 * kw + 1][0], s1l);
                u32 x3 = __shfl(pk1[2 * kw][1], s1l), y3 = __shfl(pk1[2 * kw + 1][1], s1l);
                c0 = hiH ? y0 : x0; c1 = hiH ? y1 : x1;
                c2 = hiH ? y2 : x2; c3 = hiH ? y3 : x3;
            }
            union { u32 w[4]; bf16x8 v; } pa, pb;
            pa.w[0] = a0; pa.w[1] = a1; pa.w[2] = a2; pa.w[3] = a3;
            pb.w[0] = c0; pb.w[1] = c1; pb.w[2] = c2; pb.w[3] = c3;
            #pragma unroll
            for (int dt = 0; dt < 8; ++dt) {
                bf16x8 vf = *(const bf16x8*)(bv + (16 * dt + l15) * 128 + voff[kw]);
                O0[dt] = MFMA16(pa.v, vf, O0[dt]);
                O1[dt] = MFMA16(pb.v, vf, O1[dt]);
            }
        }

        __syncthreads();
        buf ^= 1;
    }

    if (NSPLIT == 1) {
        float li0[4], li1[4];
        #pragma unroll
        for (int r = 0; r < 4; ++r) {
            li0[r] = 1.0f / __shfl(l0, 4 * g + r);
            li1[r] = 1.0f / __shfl(l1, 4 * g + r);
        }
        #pragma unroll
        for (int dt = 0; dt < 8; ++dt)
            #pragma unroll
            for (int r = 0; r < 4; ++r) {
                out[(size_t)(q0row + 4 * g + r) * DH + 16 * dt + l15]      = O0[dt][r] * li0[r];
                out[(size_t)(q0row + 16 + 4 * g + r) * DH + 16 * dt + l15] = O1[dt][r] * li1[r];
            }
    } else {
        float* op = out + (size_t)z * 16384 * DH;
        #pragma unroll
        for (int dt = 0; dt < 8; ++dt)
            #pragma unroll
            for (int r = 0; r < 4; ++r) {
                op[(size_t)(q0row + 4 * g + r) * DH + 16 * dt + l15]      = O0[dt][r];
                op[(size_t)(q0row + 16 + 4 * g + r) * DH + 16 * dt + l15] = O1[dt][r];
            }
        if (lane < 16) {
            ml[(size_t)z * 16384 + q0row + lane]      = make_float2(m0, l0);
            ml[(size_t)z * 16384 + q0row + 16 + lane] = make_float2(m1, l1);
        }
    }
}

// ---------------- Kernel 3: merge the two kt-halves ----------------
__global__ __launch_bounds__(256) void merge(
    const float* __restrict__ op, const float2* __restrict__ ml, float* __restrict__ O)
{
    int row = blockIdx.x * 16 + (threadIdx.x >> 4);
    int dq  = (threadIdx.x & 15) * 8;
    float2 a = ml[row], c = ml[16384 + row];
    float m  = fmaxf(a.x, c.x);
    float w0 = __expf(a.x - m), w1 = __expf(c.x - m);
    float inv = 1.0f / (a.y * w0 + c.y * w1);
    const float* p0 = op + (size_t)row * DH + dq;
    const float* p1 = op + (size_t)(16384 + row) * DH + dq;
    float* po = O + (size_t)row * DH + dq;
    #pragma unroll
    for (int i = 0; i < 2; ++i) {
        float4 u = *(const float4*)(p0 + 4 * i);
        float4 v = *(const float4*)(p1 + 4 * i);
        float4 o;
        o.x = (u.x * w0 + v.x * w1) * inv;
        o.y = (u.y * w0 + v.y * w1) * inv;
        o.z = (u.z * w0 + v.z * w1) * inv;
        o.w = (u.w * w0 + v.w * w1) * inv;
        *(float4*)(po + 4 * i) = o;
    }
}

extern "C" void kernel_launch(void* const* d_in, const int* in_sizes, int n_in,
                              void* d_out, int out_size, void* d_ws, size_t ws_size,
                              hipStream_t stream) {
    const float* x  = (const float*)d_in[0];
    const float* Wq = (const float*)d_in[1];
    const float* Wk = (const float*)d_in[2];
    const float* Wv = (const float*)d_in[3];
    float* out = (float*)d_out;

    const size_t SZ = (size_t)B_ * S_ * DH;     // 2,097,152 elems
    u16* qhi = (u16*)d_ws;
    u16* qlo = qhi + SZ;
    u16* khi = qlo + SZ;
    u16* klo = khi + SZ;
    u16* vtp = klo + SZ;
    u16* whi = vtp + SZ;                        // 393,216 elems each
    u16* wlo = whi + 393216;
    char* after = (char*)(wlo + 393216);
    float*  opart = (float*)after;              // 2 * 16384 * 128 f32 = 16 MB
    float2* mlp   = (float2*)(after + (size_t)2 * 16384 * 128 * 4);
    size_t need2 = (size_t)((char*)mlp - (char*)d_ws) + (size_t)2 * 16384 * 8;

    wconv<<<1536, 256, 0, stream>>>(Wq, Wk, Wv, whi, wlo);
    qkv_mfma<<<dim3(256, 3), 256, 0, stream>>>(x, whi, wlo, qhi, qlo, khi, klo, vtp);
    if (ws_size >= need2) {
        flash<2><<<256, 256, 0, stream>>>(qhi, qlo, khi, klo, vtp, opart, mlp);
        merge<<<1024, 256, 0, stream>>>(opart, mlp, out);
    } else {
        flash<1><<<128, 256, 0, stream>>>(qhi, qlo, khi, klo, vtp, out, nullptr);
    }
}